// Round 14
// baseline (191.991 us; speedup 1.0000x reference)
//
#include <hip/hip_runtime.h>
#include <hip/hip_bf16.h>
#include <math.h>

#define N_POS 4096
#define C_DIM 528
#define NHEAD 8
#define HDIM  66
#define KNN   32
#define CQKV  1584
#define KP    544      // 528 padded to 17*32
#define NP1   1664     // 1584 padded to 13*128
#define NP2   640      // 528 padded to 5*128

#define ATTN_BLOCKS  2048
#define PAIRS_PER_WAVE 4   // 2048 blocks x 4 waves x 4 = 32768 pairs

typedef __attribute__((ext_vector_type(8))) short short8;
typedef __attribute__((ext_vector_type(4))) float f32x4;
typedef __hip_bfloat16 bf16;

typedef const __attribute__((address_space(1))) void* gas1;
typedef __attribute__((address_space(3))) void* las3;

__device__ __forceinline__ short bf16bits(float f) {
    bf16 h = __float2bfloat16(f);
    return *reinterpret_cast<short*>(&h);
}
__device__ __forceinline__ short8 pack8(float4 a, float4 b) {
    short8 r;
    r[0] = bf16bits(a.x); r[1] = bf16bits(a.y);
    r[2] = bf16bits(a.z); r[3] = bf16bits(a.w);
    r[4] = bf16bits(b.x); r[5] = bf16bits(b.y);
    r[6] = bf16bits(b.z); r[7] = bf16bits(b.w);
    return r;
}

// ---------------------------------------------------------------------------
// Fused convert+GEMM (R13, unchanged): C[m][n] = sum_k A[m][k]*B[n][k]+bias.
// ---------------------------------------------------------------------------
template <bool A_F32, bool BF16OUT>
__global__ __launch_bounds__(256) void gemm_fused_kernel(
    const void* __restrict__ Av, int lda,
    const float* __restrict__ B, int Brows,
    const float* __restrict__ bias, void* __restrict__ Cv,
    int Nreal, int ldc, int nbx)
{
    __shared__ short8 As[256];
    __shared__ short8 Bs[256];

    const int tid  = threadIdx.x;
    const int lane = tid & 63;
    const int wid  = tid >> 6;

    const int nwg   = gridDim.x;
    const int chunk = nwg >> 3;
    const int swz   = (blockIdx.x & 7) * chunk + (blockIdx.x >> 3);
    const int bm = (swz / nbx) * 64;
    const int bn = (swz % nbx) * 64;

    const int r0 = tid >> 2;
    const int c0 = tid & 3;
    const int w0 = r0 * 4 + (c0 ^ (r0 & 3));
    const bool bRowOk = (bn + r0) < Brows;

    const int wm = (wid >> 1) * 32;
    const int wn = (wid & 1) * 32;
    const int arow = wm + (lane & 15);
    const int brow = wn + (lane & 15);
    const int apc  = lane >> 4;
    const int aslot = arow * 4 + (apc ^ (arow & 3));
    const int bslot = brow * 4 + (apc ^ (brow & 3));

    auto loadA = [&](int k0) -> short8 {
        const int c = k0 + c0 * 8;
        if constexpr (A_F32) {
            float4 f0 = {0.f,0.f,0.f,0.f}, f1 = {0.f,0.f,0.f,0.f};
            if (c <= C_DIM - 8) {
                const float* ap = (const float*)Av + (size_t)(bm + r0) * lda + c;
                f0 = *(const float4*)ap;
                f1 = *(const float4*)(ap + 4);
            }
            return pack8(f0, f1);
        } else {
            const bf16* ap = (const bf16*)Av + (size_t)(bm + r0) * lda + c;
            return *(const short8*)ap;
        }
    };
    auto loadB = [&](int k0) -> short8 {
        const int c = k0 + c0 * 8;
        float4 f0 = {0.f,0.f,0.f,0.f}, f1 = {0.f,0.f,0.f,0.f};
        if (c <= C_DIM - 8 && bRowOk) {
            const float* bp = B + (size_t)(bn + r0) * C_DIM + c;
            f0 = *(const float4*)bp;
            f1 = *(const float4*)(bp + 4);
        }
        return pack8(f0, f1);
    };

    f32x4 acc[2][2];
    #pragma unroll
    for (int i = 0; i < 2; ++i)
        #pragma unroll
        for (int j = 0; j < 2; ++j)
            acc[i][j] = (f32x4){0.f, 0.f, 0.f, 0.f};

    short8 a0 = loadA(0);
    short8 b0 = loadB(0);

    for (int k0 = 0;; k0 += 32) {
        As[w0] = a0;
        Bs[w0] = b0;
        __syncthreads();
        if (k0 + 32 < KP) {
            a0 = loadA(k0 + 32);
            b0 = loadB(k0 + 32);
        }
        short8 af[2], bfr[2];
        #pragma unroll
        for (int f = 0; f < 2; ++f) af[f]  = As[aslot + f * 64];
        #pragma unroll
        for (int f = 0; f < 2; ++f) bfr[f] = Bs[bslot + f * 64];
        #pragma unroll
        for (int i = 0; i < 2; ++i)
            #pragma unroll
            for (int j = 0; j < 2; ++j)
                acc[i][j] = __builtin_amdgcn_mfma_f32_16x16x32_bf16(
                    af[i], bfr[j], acc[i][j], 0, 0, 0);
        if (k0 + 32 >= KP) break;
        __syncthreads();
    }

    #pragma unroll
    for (int i = 0; i < 2; ++i) {
        const int row = bm + wm + i * 16 + (lane >> 4) * 4;
        #pragma unroll
        for (int j = 0; j < 2; ++j) {
            const int col = bn + wn + j * 16 + (lane & 15);
            if (col < Nreal) {
                const float bv = bias[col];
                #pragma unroll
                for (int rr = 0; rr < 4; ++rr) {
                    const float o = acc[i][j][rr] + bv;
                    if (BF16OUT)
                        ((bf16*)Cv)[(size_t)(row + rr) * ldc + col] = __float2bfloat16(o);
                    else
                        ((float*)Cv)[(size_t)(row + rr) * ldc + col] = o;
                }
            }
        }
    }
}

// ---------------------------------------------------------------------------
// Wave-private streaming attention. Each WAVE owns PAIRS_PER_WAVE pairs and
// a private 2x4422-float LDS region (no cross-wave data, ZERO barriers).
// Per iter: load qkv(t+1)->regs, 18x global_load_lds knn(t+1)->buf^1,
// s_waitcnt vmcnt(21) (counted: drains DMA(t), leaves t+1 streaming) +
// sched_barrier(0), then compute pair t. LDS region layout (floats):
//   [0 .. 4224)      rows 0-31: knn k|v (132 each)    <- DMA target
//   [4224 .. 4356)   row 32: [66..132) = self v       <- ds_write
//                    [0..33)  = softmax probs          <- ds_write
//   [4356 .. 4422)   q (66)                            <- ds_write
// ---------------------------------------------------------------------------
__global__ __launch_bounds__(256) void attn_kernel(
    const bf16* __restrict__ qkv, const float* __restrict__ knn,
    bf16* __restrict__ out)
{
    const float scaling = 0.12309149097933272f;  // 66^-0.5

    __shared__ float lds[4][2][4422];   // 141,504 B, 1 block/CU

    const int tid  = threadIdx.x;
    const int wv   = tid >> 6;
    const int lane = tid & 63;
    const int gbase = (blockIdx.x * 4 + wv) * PAIRS_PER_WAVE;

    float* buf0 = &lds[wv][0][0];
    float* buf1 = &lds[wv][1][0];

    // ---- DMA: 16x1KB + 2x256B = 16,896 B (rows 0-31) ----
    auto issue_dma = [&](float* dstb, int g) {
        const char* src = (const char*)(knn + (size_t)g * (KNN * 132));
        char* dst = (char*)dstb;
        #pragma unroll
        for (int i = 0; i < 16; ++i)
            __builtin_amdgcn_global_load_lds((gas1)(src + i * 1024 + lane * 16),
                                             (las3)(dst + i * 1024), 16, 0, 0);
        #pragma unroll
        for (int t2 = 0; t2 < 2; ++t2)
            __builtin_amdgcn_global_load_lds((gas1)(src + 16384 + t2 * 256 + lane * 4),
                                             (las3)(dst + 16384 + t2 * 256), 4, 0, 0);
    };
    auto load_qkv = [&](int g, float2& q2, float2& k2, float2& v2) {
        q2 = {0.f, 0.f}; k2 = {0.f, 0.f}; v2 = {0.f, 0.f};
        if (lane < 33) {
            const int n = g & 4095, h = g >> 12;
            const bf16* qp = qkv + (size_t)n * CQKV + h * HDIM + 2 * lane;
            const __hip_bfloat162 qb = *(const __hip_bfloat162*)(qp);
            const __hip_bfloat162 kb = *(const __hip_bfloat162*)(qp + C_DIM);
            const __hip_bfloat162 vb = *(const __hip_bfloat162*)(qp + 2 * C_DIM);
            q2.x = __bfloat162float(qb.x); q2.y = __bfloat162float(qb.y);
            k2.x = __bfloat162float(kb.x); k2.y = __bfloat162float(kb.y);
            v2.x = __bfloat162float(vb.x); v2.y = __bfloat162float(vb.y);
        }
    };

    // ---- prologue: pair 0 ----
    float2 q2c, k2c, v2c;
    load_qkv(gbase, q2c, k2c, v2c);
    issue_dma(buf0, gbase);

    for (int t = 0; t < PAIRS_PER_WAVE; ++t) {
        float* cur = (t & 1) ? buf1 : buf0;
        float* nxt = (t & 1) ? buf0 : buf1;
        const bool hasNext = (t + 1 < PAIRS_PER_WAVE);

        float2 q2n, k2n, v2n;
        if (hasNext) {
            load_qkv(gbase + t + 1, q2n, k2n, v2n);   // 3 vmem (pred lane<33)
            issue_dma(nxt, gbase + t + 1);            // 18 vmem
            // counted wait: drain DMA(t) + qkv(t) (older), keep 21 newest in flight
            asm volatile("s_waitcnt vmcnt(21)" ::: "memory");
        } else {
            asm volatile("s_waitcnt vmcnt(0)" ::: "memory");
        }
        __builtin_amdgcn_sched_barrier(0);

        // ---- compute pair t (wave-internal, no barriers) ----
        const int g = gbase + t;
        const int h = g >> 12;
        const int n = g & 4095;

        // norms + self-dot from held regs (idle lanes contribute 0)
        float aq = q2c.x * q2c.x + q2c.y * q2c.y;
        float ak = k2c.x * k2c.x + k2c.y * k2c.y;
        float qk = q2c.x * k2c.x + q2c.y * k2c.y;
        #pragma unroll
        for (int off = 32; off; off >>= 1) {
            aq += __shfl_xor(aq, off);
            ak += __shfl_xor(ak, off);
            qk += __shfl_xor(qk, off);
        }
        const float iq = 1.0f / fmaxf(sqrtf(aq), 1e-12f);
        const float ik = 1.0f / fmaxf(sqrtf(ak), 1e-12f);
        const float sc0  = iq * scaling;
        const float slf  = qk * iq * ik * scaling;

        // stage q and self-v into cur (disjoint from DMA rows 0-31)
        if (lane < 33) {
            *(float2*)(cur + 4356 + 2 * lane) = q2c;               // q area
            *(float2*)(cur + 32 * 132 + 66 + 2 * lane) = v2c;      // self v row
        }
        asm volatile("s_waitcnt lgkmcnt(0)" ::: "memory");
        __builtin_amdgcn_sched_barrier(0);

        // dots: 2 lanes per key, 33 dims each
        const int j  = lane >> 1;
        const int l2 = lane & 1;
        {
            const float* kr = cur + j * 132 + l2;
            const float* Qp = cur + 4356 + l2;
            float p = 0.f;
            #pragma unroll
            for (int d = 0; d < 33; ++d) p += Qp[2 * d] * kr[2 * d];
            p += __shfl_xor(p, 1);
            p *= sc0;

            // softmax over 32 knn logits (pair-replicated) + self
            float m = p;
            #pragma unroll
            for (int off = 2; off <= 32; off <<= 1) m = fmaxf(m, __shfl_xor(m, off));
            m = fmaxf(m, slf);
            const float e = __expf(p - m);
            float S = e;
            #pragma unroll
            for (int off = 2; off <= 32; off <<= 1) S += __shfl_xor(S, off);
            const float es = __expf(slf - m);
            const float tot = S + es;
            float* sp = cur + 32 * 132;            // probs area
            if (l2 == 0) sp[j] = e / tot;
            if (lane == 0) sp[32] = es / tot;
        }
        asm volatile("s_waitcnt lgkmcnt(0)" ::: "memory");
        __builtin_amdgcn_sched_barrier(0);

        // PV: lanes 0-32 each handle dims {2l, 2l+1}; rows 0-32 (32 = self v)
        if (lane < 33) {
            const float* sp = cur + 32 * 132;
            const float* vr = cur + 66 + 2 * lane;
            float2 acc = {0.f, 0.f};
            #pragma unroll
            for (int jj = 0; jj < 33; ++jj) {
                const float pj = sp[jj];
                const float2 vj = *(const float2*)(vr + jj * 132);
                acc.x += pj * vj.x;
                acc.y += pj * vj.y;
            }
            __hip_bfloat162 o2;
            o2.x = __float2bfloat16(acc.x);
            o2.y = __float2bfloat16(acc.y);
            *(__hip_bfloat162*)(out + (size_t)n * KP + h * HDIM + 2 * lane) = o2;
        } else if (h == 0 && lane < 49) {
            out[(size_t)n * KP + C_DIM + (lane - 33)] = __float2bfloat16(0.f);
        }

        q2c = q2n; k2c = k2n; v2c = v2n;
    }
}

extern "C" void kernel_launch(void* const* d_in, const int* in_sizes, int n_in,
                              void* d_out, int out_size, void* d_ws, size_t ws_size,
                              hipStream_t stream)
{
    const float* x      = (const float*)d_in[0];
    const float* knn_kv = (const float*)d_in[1];
    const float* w_qkv  = (const float*)d_in[2];
    const float* b_qkv  = (const float*)d_in[3];
    const float* w_proj = (const float*)d_in[4];
    const float* b_proj = (const float*)d_in[5];
    float* out = (float*)d_out;

    char* ws = (char*)d_ws;
    bf16* qkvb = (bf16*)ws;                  // 4096*1584*2 = 12,976,128 B
    bf16* ab   = (bf16*)(ws + 12976128);     // 4096*544*2  =  4,456,448 B

    gemm_fused_kernel<true, true>
        <<<dim3((NP1 / 64) * (N_POS / 64)), 256, 0, stream>>>(
        x, C_DIM, w_qkv, CQKV, b_qkv, qkvb, CQKV, CQKV, NP1 / 64);

    attn_kernel<<<dim3(ATTN_BLOCKS), 256, 0, stream>>>(qkvb, knn_kv, ab);

    gemm_fused_kernel<false, false>
        <<<dim3((NP2 / 64) * (N_POS / 64)), 256, 0, stream>>>(
        ab, KP, w_proj, C_DIM, b_proj, out, C_DIM, C_DIM, NP2 / 64);
}